// Round 7
// baseline (253.564 us; speedup 1.0000x reference)
//
#include <hip/hip_runtime.h>
#include <hip/hip_bf16.h>

typedef short s16x8 __attribute__((ext_vector_type(8)));
typedef float f32x4 __attribute__((ext_vector_type(4)));
typedef unsigned short u16x8 __attribute__((ext_vector_type(8)));

static constexpr int Bc   = 8;
static constexpr int Nn   = 24576;
static constexpr int Kk   = 16;
static constexpr int Cc   = 64;
static constexpr int Rr   = Bc * Nn;     // 196608
static constexpr float EPS = 1e-5f;

__device__ __forceinline__ unsigned short f2bf(float f) {
    union { float f; unsigned int u; } c; c.f = f;
    unsigned int r = c.u + 0x7FFFu + ((c.u >> 16) & 1u);  // RNE
    return (unsigned short)(r >> 16);
}
__device__ __forceinline__ float bf2f(unsigned short u) {
    union { unsigned int u; float f; } c; c.u = ((unsigned int)u) << 16; return c.f;
}
// bf16-pair unpack: low half = 1 shift, high half = 1 and
__device__ __forceinline__ float bflo(unsigned g) {
    union { unsigned u; float f; } c; c.u = g << 16; return c.f;
}
__device__ __forceinline__ float bfhi(unsigned g) {
    union { unsigned u; float f; } c; c.u = g & 0xffff0000u; return c.f;
}
__device__ __forceinline__ unsigned packbf(float lo, float hi) {
    return (unsigned)f2bf(lo) | ((unsigned)f2bf(hi) << 16);
}

// ---------------------------------------------------------------------------
// K1: h = x · W^T via MFMA (bf16 in, fp32 acc, bf16 out).
// XCD-batch partition: batch = bid%8. Block 0 also zeroes the stats
// accumulator (stream order guarantees it's done before K2 starts).
// ---------------------------------------------------------------------------
__global__ __launch_bounds__(256) void linear_mfma_kernel(
    const float* __restrict__ x, const float* __restrict__ W,
    __hip_bfloat16* __restrict__ h, float* __restrict__ stats)
{
    if (blockIdx.x == 0 && threadIdx.x < 128) stats[threadIdx.x] = 0.f;

    const int tid  = threadIdx.x;
    const int l    = tid & 63;
    const int wave = tid >> 6;
    const int batch = blockIdx.x & 7;          // -> XCD (round-robin dispatch)
    const int qb    = blockIdx.x >> 3;         // 0..255
    const int wib   = qb * 4 + wave;           // wave-in-batch 0..1023

    const int lr = l & 15;
    const int kg = (l >> 4) * 8;
    const int dr = (l >> 4) * 4;

    s16x8 bfrag[4][2];
#pragma unroll
    for (int ct = 0; ct < 4; ++ct)
#pragma unroll
        for (int kc = 0; kc < 2; ++kc) {
            const float* bp = W + (ct * 16 + lr) * 64 + kc * 32 + kg;
            f32x4 b0 = *reinterpret_cast<const f32x4*>(bp);
            f32x4 b1 = *reinterpret_cast<const f32x4*>(bp + 4);
            s16x8 f;
            f[0] = (short)f2bf(b0[0]); f[1] = (short)f2bf(b0[1]);
            f[2] = (short)f2bf(b0[2]); f[3] = (short)f2bf(b0[3]);
            f[4] = (short)f2bf(b1[0]); f[5] = (short)f2bf(b1[1]);
            f[6] = (short)f2bf(b1[2]); f[7] = (short)f2bf(b1[3]);
            bfrag[ct][kc] = f;
        }

    unsigned short* hu = (unsigned short*)h;
    const int tiles_per_batch = Nn / 16;       // 1536
    for (int t = wib; t < tiles_per_batch; t += 1024) {
        const int row0 = batch * Nn + t * 16;
        const float* ap = x + (size_t)(row0 + lr) * 64 + kg;
        f32x4 a0 = *reinterpret_cast<const f32x4*>(ap);
        f32x4 a1 = *reinterpret_cast<const f32x4*>(ap + 4);
        f32x4 a2 = *reinterpret_cast<const f32x4*>(ap + 32);
        f32x4 a3 = *reinterpret_cast<const f32x4*>(ap + 36);
        s16x8 fa0, fa1;
        fa0[0] = (short)f2bf(a0[0]); fa0[1] = (short)f2bf(a0[1]);
        fa0[2] = (short)f2bf(a0[2]); fa0[3] = (short)f2bf(a0[3]);
        fa0[4] = (short)f2bf(a1[0]); fa0[5] = (short)f2bf(a1[1]);
        fa0[6] = (short)f2bf(a1[2]); fa0[7] = (short)f2bf(a1[3]);
        fa1[0] = (short)f2bf(a2[0]); fa1[1] = (short)f2bf(a2[1]);
        fa1[2] = (short)f2bf(a2[2]); fa1[3] = (short)f2bf(a2[3]);
        fa1[4] = (short)f2bf(a3[0]); fa1[5] = (short)f2bf(a3[1]);
        fa1[6] = (short)f2bf(a3[2]); fa1[7] = (short)f2bf(a3[3]);

        f32x4 acc[4];
#pragma unroll
        for (int ct = 0; ct < 4; ++ct) { acc[ct] = (f32x4){0.f, 0.f, 0.f, 0.f}; }
#pragma unroll
        for (int ct = 0; ct < 4; ++ct) {
            acc[ct] = __builtin_amdgcn_mfma_f32_16x16x32_bf16(fa0, bfrag[ct][0], acc[ct], 0, 0, 0);
            acc[ct] = __builtin_amdgcn_mfma_f32_16x16x32_bf16(fa1, bfrag[ct][1], acc[ct], 0, 0, 0);
        }
#pragma unroll
        for (int ct = 0; ct < 4; ++ct)
#pragma unroll
            for (int r = 0; r < 4; ++r)
                hu[(size_t)(row0 + dr + r) * 64 + ct * 16 + lr] = f2bf(acc[ct][r]);
    }
}

// ---------------------------------------------------------------------------
// K2: v[r][o] = (max_k h[nbr(r,k)][o]) - h[r][o], bf16 in/out.
// lane = channel-PAIR (u32 = 2 bf16), half-wave = row. 4 rows per iteration:
// 32 dword gathers in flight, each 256 B coalesced (2x128 B segments).
// batch = bid%8 keeps gathers on the XCD whose L2 holds the 3 MB h slice.
// ---------------------------------------------------------------------------
__global__ __launch_bounds__(256) void gather_bn_kernel(
    const __hip_bfloat16* __restrict__ h, const int* __restrict__ knn,
    __hip_bfloat16* __restrict__ v, float* __restrict__ stats)
{
    const int tid   = threadIdx.x;
    const int l     = tid & 63;
    const int wave  = tid >> 6;
    const int batch = blockIdx.x & 7;
    const int qb    = blockIdx.x >> 3;
    const int wib   = qb * 4 + wave;           // 0..1023

    const unsigned* hu32 = (const unsigned*)h;
    unsigned* vu32 = (unsigned*)v;
    const int bbase = batch * Nn;

    const int half = l >> 5;                   // 0 or 1: which row of a pair
    const int c2   = l & 31;                   // channel pair (2*c2, 2*c2+1)
    const int kl   = l & 15;

    float sum_lo = 0.f, sum_hi = 0.f, sq_lo = 0.f, sq_hi = 0.f;

    for (int r = wib * 4; r < Nn; r += 4096) { // 6 iterations
        const int rowA = bbase + r + half;         // pair 1: rows r, r+1
        const int rowC = bbase + r + 2 + half;     // pair 2: rows r+2, r+3
        const int ia = knn[(size_t)rowA * Kk + kl];
        const int ic = knn[(size_t)rowC * Kk + kl];
        const unsigned oa = hu32[(size_t)rowA * 32 + c2];
        const unsigned oc = hu32[(size_t)rowC * 32 + c2];
        float mAlo = -3e38f, mAhi = -3e38f, mClo = -3e38f, mChi = -3e38f;
#pragma unroll
        for (int k = 0; k < Kk; ++k) {
            const int ja = __shfl(ia, (l & 32) + k);   // ds_bpermute
            const int jc = __shfl(ic, (l & 32) + k);
            const unsigned ga = hu32[(size_t)(bbase + ja) * 32 + c2];
            const unsigned gc = hu32[(size_t)(bbase + jc) * 32 + c2];
            mAlo = fmaxf(mAlo, bflo(ga)); mAhi = fmaxf(mAhi, bfhi(ga));
            mClo = fmaxf(mClo, bflo(gc)); mChi = fmaxf(mChi, bfhi(gc));
        }
        const float vAlo = mAlo - bflo(oa), vAhi = mAhi - bfhi(oa);
        const float vClo = mClo - bflo(oc), vChi = mChi - bfhi(oc);
        vu32[(size_t)rowA * 32 + c2] = packbf(vAlo, vAhi);
        vu32[(size_t)rowC * 32 + c2] = packbf(vClo, vChi);
        sum_lo += vAlo + vClo; sum_hi += vAhi + vChi;
        sq_lo  += vAlo * vAlo + vClo * vClo;
        sq_hi  += vAhi * vAhi + vChi * vChi;
    }

    // lanes l and l^32 hold the same channel pair (different rows): combine
    sum_lo += __shfl_xor(sum_lo, 32); sum_hi += __shfl_xor(sum_hi, 32);
    sq_lo  += __shfl_xor(sq_lo, 32);  sq_hi  += __shfl_xor(sq_hi, 32);

    __shared__ float s[4][4][32];  // [stat][wave][c2]
    if (half == 0) {
        s[0][wave][c2] = sum_lo; s[1][wave][c2] = sum_hi;
        s[2][wave][c2] = sq_lo;  s[3][wave][c2] = sq_hi;
    }
    __syncthreads();
    if (wave == 0 && half == 0) {
        const float a0 = s[0][0][c2] + s[0][1][c2] + s[0][2][c2] + s[0][3][c2];
        const float a1 = s[1][0][c2] + s[1][1][c2] + s[1][2][c2] + s[1][3][c2];
        const float q0 = s[2][0][c2] + s[2][1][c2] + s[2][2][c2] + s[2][3][c2];
        const float q1 = s[3][0][c2] + s[3][1][c2] + s[3][2][c2] + s[3][3][c2];
        atomicAdd(&stats[2 * c2],      a0);
        atomicAdd(&stats[2 * c2 + 1],  a1);
        atomicAdd(&stats[64 + 2 * c2], q0);
        atomicAdd(&stats[64 + 2 * c2 + 1], q1);
    }
}

// ---------------------------------------------------------------------------
// K3 (was K4): out = v_bf16 * scale[c] + shift[c]. scale/shift computed
// per-block from stats (trivial redundant work, kills a dispatch).
// Same batch partition: v read from the XCD L2 that K2 wrote through.
// ---------------------------------------------------------------------------
__global__ __launch_bounds__(256) void norm_kernel(
    const __hip_bfloat16* __restrict__ v, const float* __restrict__ stats,
    const float* __restrict__ gamma, const float* __restrict__ beta,
    float* __restrict__ out)
{
    __shared__ float sc[64], sh[64];
    if (threadIdx.x < 64) {
        const int o = threadIdx.x;
        const float inv = 1.0f / (float)Rr;
        const float mean = stats[o] * inv;
        const float var  = stats[64 + o] * inv - mean * mean;
        const float s    = gamma[o] * rsqrtf(var + EPS);
        sc[o] = s;
        sh[o] = beta[o] - mean * s;
    }
    __syncthreads();

    const int batch = blockIdx.x & 7;
    const int qb    = blockIdx.x >> 3;          // 0..255
    const u16x8* vu = (const u16x8*)v;
    const int per_batch8 = Nn * 64 / 8;         // groups of 8 elems per batch
    const size_t base8 = (size_t)batch * per_batch8;

    for (int li = qb * 256 + threadIdx.x; li < per_batch8; li += 256 * 256) {
        const size_t i = base8 + li;
        u16x8 t = vu[i];
        const int c = (li * 8) & 63;
        f32x4 r0, r1;
        r0[0] = bf2f(t[0]) * sc[c + 0] + sh[c + 0];
        r0[1] = bf2f(t[1]) * sc[c + 1] + sh[c + 1];
        r0[2] = bf2f(t[2]) * sc[c + 2] + sh[c + 2];
        r0[3] = bf2f(t[3]) * sc[c + 3] + sh[c + 3];
        r1[0] = bf2f(t[4]) * sc[c + 4] + sh[c + 4];
        r1[1] = bf2f(t[5]) * sc[c + 5] + sh[c + 5];
        r1[2] = bf2f(t[6]) * sc[c + 6] + sh[c + 6];
        r1[3] = bf2f(t[7]) * sc[c + 7] + sh[c + 7];
        f32x4* op = reinterpret_cast<f32x4*>(out + i * 8);
        __builtin_nontemporal_store(r0, op);
        __builtin_nontemporal_store(r1, op + 1);
    }
}

// ---------------------------------------------------------------------------
extern "C" void kernel_launch(void* const* d_in, const int* in_sizes, int n_in,
                              void* d_out, int out_size, void* d_ws, size_t ws_size,
                              hipStream_t stream)
{
    const float* x     = (const float*)d_in[0];
    const float* W     = (const float*)d_in[1];
    const float* gamma = (const float*)d_in[2];
    const float* beta  = (const float*)d_in[3];
    const int*   knn   = (const int*)d_in[4];
    float*       out   = (float*)d_out;

    // ws layout: h bf16 [Rr*64] | v bf16 [Rr*64] | stats[128]
    __hip_bfloat16* h = (__hip_bfloat16*)d_ws;
    __hip_bfloat16* v = h + (size_t)Rr * 64;
    float* stats = (float*)((char*)d_ws + 2 * (size_t)Rr * 64 * sizeof(__hip_bfloat16));

    linear_mfma_kernel<<<2048, 256, 0, stream>>>(x, W, h, stats);
    gather_bn_kernel<<<2048, 256, 0, stream>>>(h, knn, v, stats);
    norm_kernel<<<2048, 256, 0, stream>>>(v, stats, gamma, beta, out);
}